// Round 12
// baseline (215.156 us; speedup 1.0000x reference)
//
#include <hip/hip_runtime.h>
#include <stdint.h>

#define NB 2
#define NH 12
#define NS 2048
#define ND 64

typedef __attribute__((ext_vector_type(4))) float f32x4;
typedef __attribute__((ext_vector_type(8))) short s16x8;

__device__ __forceinline__ short f2bf(float x) {
    return __builtin_bit_cast(short, (__bf16)x);
}
__device__ __forceinline__ float bf2f(short h) {
    uint32_t u = ((uint32_t)(unsigned short)h) << 16;
    return __builtin_bit_cast(float, u);
}
__device__ __forceinline__ f32x4 mfma16(s16x8 a, s16x8 b, f32x4 c) {
    return __builtin_amdgcn_mfma_f32_16x16x32_bf16(a, b, c, 0, 0, 0);
}

// ---------- pre-pass 1: mask int32 -> bitmask, 1 MB ----------
__global__ void kbits(const int* __restrict__ maskg, uint32_t* __restrict__ bits) {
    int wi = blockIdx.x * 256 + threadIdx.x;
    const int* mp = maskg + (size_t)wi * 32;
    uint32_t v = 0;
#pragma unroll
    for (int i = 0; i < 8; i++) {
        int4 q = *(const int4*)(mp + i * 4);
        v |= ((uint32_t)(q.x != 0) << (i * 4)) | ((uint32_t)(q.y != 0) << (i * 4 + 1)) |
             ((uint32_t)(q.z != 0) << (i * 4 + 2)) | ((uint32_t)(q.w != 0) << (i * 4 + 3));
    }
    bits[wi] = v;
}

// ---------- pre-pass 2: VwT[b,h,d,k] = V[b,h,k,d]*w[k] bf16, 6.3 MB ----------
__global__ void kvwt(const float* __restrict__ Vg, const float* __restrict__ wg,
                     unsigned short* __restrict__ vwt) {
    __shared__ float tile[32][65];
    int blk = blockIdx.x;
    int bh = blk >> 6;
    int k0 = (blk & 63) * 32;
    const float* Vh = Vg + ((size_t)bh * NS + k0) * ND;
    int t = threadIdx.x;
    {
        int kk = t >> 3, c = (t & 7) * 8;
        f32x4 a = *(const f32x4*)(Vh + kk * ND + c);
        f32x4 b4 = *(const f32x4*)(Vh + kk * ND + c + 4);
        float wk = wg[k0 + kk];
#pragma unroll
        for (int j = 0; j < 4; j++) {
            tile[kk][c + j] = a[j] * wk;
            tile[kk][c + 4 + j] = b4[j] * wk;
        }
    }
    __syncthreads();
    {
        int d = t >> 2, kb2 = (t & 3) * 8;
        s16x8 o;
#pragma unroll
        for (int j = 0; j < 8; j++) o[j] = f2bf(tile[kb2 + j][d]);
        *(s16x8*)(vwt + ((size_t)bh * ND + d) * NS + k0 + kb2) = o;
    }
}

// ---------- pre-pass 3: K f32 -> bf16, 6.3 MB ----------
__global__ void kcast(const float* __restrict__ in, unsigned short* __restrict__ outp) {
    size_t t = (size_t)blockIdx.x * 256 + threadIdx.x;
    const float* p = in + t * 8;
    f32x4 a = *(const f32x4*)p;
    f32x4 b = *(const f32x4*)(p + 4);
    s16x8 o;
#pragma unroll
    for (int j = 0; j < 4; j++) {
        o[j] = f2bf(a[j]);
        o[4 + j] = f2bf(b[j]);
    }
    *(s16x8*)(outp + t * 8) = o;
}

// ---------- main: 32-row tiles, phase-separated reads vs stores ----------
// WG = 1024 thr (16 waves), 32 q-rows, 1 WG/CU (155 KB LDS).
// Phase A (global READS only): all 16 waves QK own 128-k strip -> bf16 P in
// LDS + ssum. Barrier; rinv; barrier.
// Phase B (global READS only): waves 0-7 PV with (dt = wv&3, k-half = wv>>2)
// split; partial f32x4 sums -> pO[2][32][68] LDS. Barrier.
// Phase C (global STORES only, zero global loads on the CU): out reduce by
// first 512 threads, then ALL 16 waves stream 2 p_attn rows each from LDS.
// This gives the store phase the fill-kernel regime (pure store stream),
// which sustains 6.8 TB/s vs ~2.4 TB/s under mixed read/store traffic.
__global__ __launch_bounds__(1024, 4) void attn_main(
    const float* __restrict__ Qg, const float* __restrict__ wg,
    const uint32_t* __restrict__ bitsg, const unsigned short* __restrict__ vwtg,
    const unsigned short* __restrict__ kbfg, float* __restrict__ outg,
    float* __restrict__ pg) {
    extern __shared__ char smem[];
    char* Pb = smem;                           // [32][4096 B] bf16 = 131072
    float* w_lds = (float*)(smem + 131072);    // [2048] f32 = 8192
    float* pO = (float*)(smem + 139264);       // [2][32][68] f32 = 17408
    float* red = (float*)(smem + 156672);      // [16][32] = 2048
    float* rinv_sh = (float*)(smem + 158720);  // [32] = 128

    int bid = blockIdx.x;
    // XCD swizzle: 1536 WGs = 8 x 192 (bijective); 1.5 heads/XCD L2-resident
    int swz = (bid & 7) * 192 + (bid >> 3);
    int bh = swz >> 6;
    int qb = swz & 63;
    int b = bh / NH;
    int q0 = qb * 32;

    const unsigned short* kbfh = kbfg + (size_t)bh * NS * ND;
    const uint32_t* bitsb = bitsg + (size_t)b * (NS * (NS / 32));
    float* ph = pg + ((size_t)bh * NS + q0) * NS;
    float* outh = outg + (size_t)bh * NS * ND;

    int tid = threadIdx.x;
    int wv = tid >> 6, lane = tid & 63;
    int m = lane & 15, kb = lane >> 4;
    const int xm = (m & 7) << 4;  // == (q&7)<<4 for q = n*16+m

    // stage w into LDS (visible after rms barrier)
    if (tid < 512) *(f32x4*)(w_lds + tid * 4) = *(const f32x4*)(wg + tid * 4);

    // Q fragments for both 16-row groups (1/8 folded)
    s16x8 qf[2][2];
#pragma unroll
    for (int n = 0; n < 2; n++)
#pragma unroll
        for (int ks = 0; ks < 2; ks++) {
            const float* src = Qg + ((size_t)bh * NS + q0 + n * 16 + m) * ND + ks * 32 + kb * 8;
            f32x4 a = *(const f32x4*)src;
            f32x4 c4 = *(const f32x4*)(src + 4);
            s16x8 f;
#pragma unroll
            for (int j = 0; j < 4; j++) {
                f[j] = f2bf(a[j] * 0.125f);
                f[4 + j] = f2bf(c4[j] * 0.125f);
            }
            qf[n][ks] = f;
        }

    // ---- Phase A: all 16 waves QK own 128-k strip (reads only) ----
    float ssum[2] = {0.f, 0.f};
    const int cbase = wv * 128;
#pragma unroll 4
    for (int kt = 0; kt < 8; kt++) {
        int krow = cbase + kt * 16;
        const unsigned short* kr = kbfh + (size_t)(krow + m) * ND + kb * 8;
        s16x8 kf0 = *(const s16x8*)kr;
        s16x8 kf1 = *(const s16x8*)(kr + 32);
        f32x4 c0 = {0.f, 0.f, 0.f, 0.f}, c1 = {0.f, 0.f, 0.f, 0.f};
        c0 = mfma16(kf0, qf[0][0], c0);
        c0 = mfma16(kf1, qf[0][1], c0);
        c1 = mfma16(kf0, qf[1][0], c1);
        c1 = mfma16(kf1, qf[1][1], c1);
        int kcol = krow + kb * 4;
#pragma unroll
        for (int n = 0; n < 2; n++) {
            f32x4 c = n ? c1 : c0;
            int q = n * 16 + m;
            uint32_t word = bitsb[(size_t)(q0 + q) * (NS / 32) + (kcol >> 5)];
            uint32_t keepbits = word >> (kcol & 31);
            float p[4];
#pragma unroll
            for (int r = 0; r < 4; r++) {
                float s = c[r];
                bool keep = ((keepbits >> r) & 1u) && (s > 0.f);
                p[r] = keep ? s : 0.f;
                ssum[n] += p[r] * p[r];
            }
            uint2 u;
            u.x = (uint32_t)(unsigned short)f2bf(p[0]) |
                  ((uint32_t)(unsigned short)f2bf(p[1]) << 16);
            u.y = (uint32_t)(unsigned short)f2bf(p[2]) |
                  ((uint32_t)(unsigned short)f2bf(p[3]) << 16);
            *(uint2*)(Pb + q * 4096 + ((kcol * 2) ^ xm)) = u;
        }
    }
    ssum[0] += __shfl_xor(ssum[0], 16);
    ssum[0] += __shfl_xor(ssum[0], 32);
    ssum[1] += __shfl_xor(ssum[1], 16);
    ssum[1] += __shfl_xor(ssum[1], 32);
    if (lane < 16) {
        red[wv * 32 + lane] = ssum[0];
        red[wv * 32 + 16 + lane] = ssum[1];
    }
    __syncthreads();
    if (tid < 32) {
        float s = 0.f;
#pragma unroll
        for (int i = 0; i < 16; i++) s += red[i * 32 + tid];
        rinv_sh[tid] = 1.0f / sqrtf(s * (1.0f / NS) + 1e-6f);
    }
    __syncthreads();

    // ---- Phase B: PV partials, 8 waves (dt x k-half), reads only ----
    if (wv < 8) {
        const int dt = wv & 3;
        const int kh = wv >> 2;
        const unsigned short* vrow = vwtg + ((size_t)bh * ND + dt * 16 + m) * NS + kh * 1024;
        f32x4 acc[2][2];
#pragma unroll
        for (int n = 0; n < 2; n++)
#pragma unroll
            for (int h = 0; h < 2; h++) acc[n][h] = (f32x4){0.f, 0.f, 0.f, 0.f};
#pragma unroll 4
        for (int ks = 0; ks < 16; ks++) {
            int k0 = ks * 64;
            s16x8 af0 = *(const s16x8*)(vrow + k0 + kb * 8);
            s16x8 af1 = *(const s16x8*)(vrow + k0 + 32 + kb * 8);
            int kbyte = (kh * 1024 + k0) * 2;
#pragma unroll
            for (int n = 0; n < 2; n++) {
                int q = n * 16 + m;
                s16x8 b0 = *(const s16x8*)(Pb + q * 4096 + ((kbyte + kb * 16) ^ xm));
                s16x8 b1 = *(const s16x8*)(Pb + q * 4096 + ((kbyte + 64 + kb * 16) ^ xm));
                acc[n][0] = mfma16(af0, b0, acc[n][0]);
                acc[n][1] = mfma16(af1, b1, acc[n][1]);
            }
        }
#pragma unroll
        for (int n = 0; n < 2; n++) {
            int q = n * 16 + m;
            f32x4 s = {acc[n][0][0] + acc[n][1][0], acc[n][0][1] + acc[n][1][1],
                       acc[n][0][2] + acc[n][1][2], acc[n][0][3] + acc[n][1][3]};
            *(f32x4*)(pO + (size_t)(kh * 32 + q) * 68 + dt * 16 + kb * 4) = s;
        }
    }
    __syncthreads();

    // ---- Phase C: pure stores (out reduce + p_attn stream), no global loads --
    if (tid < 512) {
        int q = tid >> 4, dq = (tid & 15) * 4;
        f32x4 a = *(const f32x4*)(pO + (size_t)q * 68 + dq);
        f32x4 b2 = *(const f32x4*)(pO + (size_t)(32 + q) * 68 + dq);
        float ri = rinv_sh[q];
        f32x4 o = {(a[0] + b2[0]) * ri, (a[1] + b2[1]) * ri, (a[2] + b2[2]) * ri,
                   (a[3] + b2[3]) * ri};
        __builtin_nontemporal_store(o, (f32x4*)(outh + (size_t)(q0 + q) * ND + dq));
    }
#pragma unroll
    for (int rr = 0; rr < 2; rr++) {
        int r = wv * 2 + rr;
        float ri = rinv_sh[r];
        int xr = (r & 7) << 4;
#pragma unroll
        for (int it = 0; it < 8; it++) {
            int colf = it * 256 + lane * 4;
            uint2 u = *(const uint2*)(Pb + r * 4096 + ((colf * 2) ^ xr));
            f32x4 w4 = *(const f32x4*)(w_lds + colf);
            f32x4 o;
            o[0] = bf2f((short)(u.x & 0xffff)) * w4[0] * ri;
            o[1] = bf2f((short)(u.x >> 16)) * w4[1] * ri;
            o[2] = bf2f((short)(u.y & 0xffff)) * w4[2] * ri;
            o[3] = bf2f((short)(u.y >> 16)) * w4[3] * ri;
            __builtin_nontemporal_store(o, (f32x4*)(ph + (size_t)r * NS + colf));
        }
    }
}

// ---------- fallback (no workspace): fp32-exact per-row kernel ----------
__global__ void attn_fallback(const float* __restrict__ Qg, const float* __restrict__ Kg,
                              const float* __restrict__ Vg, const int* __restrict__ maskg,
                              const float* __restrict__ wg, float* __restrict__ outg,
                              float* __restrict__ pg) {
    __shared__ float qs[64];
    __shared__ float srow[2048];
    __shared__ float osum[64];
    __shared__ float red2[8];
    int bid = blockIdx.x;
    int bh = bid >> 11, q = bid & 2047, b = bh / NH;
    int tid = threadIdx.x;
    const float* Qr = Qg + ((size_t)bh * NS + q) * ND;
    const float* Kh = Kg + (size_t)bh * NS * ND;
    const float* Vh = Vg + (size_t)bh * NS * ND;
    const int* mrow = maskg + ((size_t)b * NS + q) * NS;
    if (tid < 64) {
        qs[tid] = Qr[tid] * 0.125f;
        osum[tid] = 0.f;
    }
    __syncthreads();
    float ss = 0.f;
    for (int k = tid; k < NS; k += 256) {
        float s = 0.f;
        const float* kr = Kh + (size_t)k * ND;
        for (int d = 0; d < ND; d++) s += qs[d] * kr[d];
        if (mrow[k] == 0 || s < 0.f) s = 0.f;
        srow[k] = s;
        ss += s * s;
    }
#pragma unroll
    for (int o = 32; o >= 1; o >>= 1) ss += __shfl_down(ss, o);
    if ((tid & 63) == 0) red2[tid >> 6] = ss;
    __syncthreads();
    float ri;
    {
        float tot = red2[0] + red2[1] + red2[2] + red2[3];
        ri = 1.0f / sqrtf(tot * (1.0f / NS) + 1e-6f);
    }
    for (int k = tid; k < NS; k += 256) {
        float pa = srow[k] * ri * wg[k];
        pg[(((size_t)bh * NS + q) * NS) + k] = pa;
        const float* vr = Vh + (size_t)k * ND;
        for (int d = 0; d < ND; d++) atomicAdd(&osum[d], pa * vr[d]);
    }
    __syncthreads();
    if (tid < 64) outg[((size_t)bh * NS + q) * ND + tid] = osum[tid];
}

extern "C" void kernel_launch(void* const* d_in, const int* in_sizes, int n_in,
                              void* d_out, int out_size, void* d_ws, size_t ws_size,
                              hipStream_t stream) {
    const float* Q = (const float*)d_in[0];
    const float* K = (const float*)d_in[1];
    const float* V = (const float*)d_in[2];
    const int* mask = (const int*)d_in[3];
    const float* w = (const float*)d_in[4];
    float* out = (float*)d_out;
    float* pattn = out + (size_t)NB * NH * NS * ND;

    const size_t bits_bytes = (size_t)NB * NS * (NS / 32) * sizeof(uint32_t);     // 1 MB
    const size_t vwt_bytes = (size_t)NB * NH * ND * NS * sizeof(unsigned short);  // 6.3 MB
    const size_t kbf_bytes = vwt_bytes;                                           // 6.3 MB
    const int nwg = NB * NH * (NS / 32);  // 1536
    const int smem = 131072 + 8192 + 17408 + 2048 + 128;  // 158848 B

    if (ws_size >= bits_bytes + vwt_bytes + kbf_bytes) {
        char* wsb = (char*)d_ws;
        uint32_t* bits = (uint32_t*)wsb;
        unsigned short* vwt = (unsigned short*)(wsb + bits_bytes);
        unsigned short* kbf = (unsigned short*)(wsb + bits_bytes + vwt_bytes);
        kbits<<<(NB * NS * NS / 32) / 256, 256, 0, stream>>>(mask, bits);
        kcast<<<(NB * NH * NS * ND) / (256 * 8), 256, 0, stream>>>(K, kbf);
        kvwt<<<NB * NH * (NS / 32), 256, 0, stream>>>(V, w, vwt);
        hipFuncSetAttribute(reinterpret_cast<const void*>(&attn_main),
                            hipFuncAttributeMaxDynamicSharedMemorySize, smem);
        attn_main<<<nwg, 1024, smem, stream>>>(Q, w, bits, vwt, kbf, out, pattn);
    } else {
        attn_fallback<<<NB * NH * NS, 256, 0, stream>>>(Q, K, V, mask, w, out, pattn);
    }
}

// Round 13
// 165.754 us; speedup vs baseline: 1.2980x; 1.2980x over previous
//
#include <hip/hip_runtime.h>
#include <stdint.h>

#define NB 2
#define NH 12
#define NS 2048
#define ND 64

typedef __attribute__((ext_vector_type(4))) float f32x4;
typedef __attribute__((ext_vector_type(8))) short s16x8;

__device__ __forceinline__ short f2bf(float x) {
    return __builtin_bit_cast(short, (__bf16)x);
}
__device__ __forceinline__ float bf2f(short h) {
    uint32_t u = ((uint32_t)(unsigned short)h) << 16;
    return __builtin_bit_cast(float, u);
}
__device__ __forceinline__ f32x4 mfma16(s16x8 a, s16x8 b, f32x4 c) {
    return __builtin_amdgcn_mfma_f32_16x16x32_bf16(a, b, c, 0, 0, 0);
}

// ---------- pre-pass 1: mask int32 -> bitmask, 1 MB ----------
__global__ void kbits(const int* __restrict__ maskg, uint32_t* __restrict__ bits) {
    int wi = blockIdx.x * 256 + threadIdx.x;
    const int* mp = maskg + (size_t)wi * 32;
    uint32_t v = 0;
#pragma unroll
    for (int i = 0; i < 8; i++) {
        int4 q = *(const int4*)(mp + i * 4);
        v |= ((uint32_t)(q.x != 0) << (i * 4)) | ((uint32_t)(q.y != 0) << (i * 4 + 1)) |
             ((uint32_t)(q.z != 0) << (i * 4 + 2)) | ((uint32_t)(q.w != 0) << (i * 4 + 3));
    }
    bits[wi] = v;
}

// ---------- pre-pass 2: VwT[b,h,d,k] = V[b,h,k,d]*w[k] bf16, 6.3 MB ----------
__global__ void kvwt(const float* __restrict__ Vg, const float* __restrict__ wg,
                     unsigned short* __restrict__ vwt) {
    __shared__ float tile[32][65];
    int blk = blockIdx.x;
    int bh = blk >> 6;
    int k0 = (blk & 63) * 32;
    const float* Vh = Vg + ((size_t)bh * NS + k0) * ND;
    int t = threadIdx.x;
    {
        int kk = t >> 3, c = (t & 7) * 8;
        f32x4 a = *(const f32x4*)(Vh + kk * ND + c);
        f32x4 b4 = *(const f32x4*)(Vh + kk * ND + c + 4);
        float wk = wg[k0 + kk];
#pragma unroll
        for (int j = 0; j < 4; j++) {
            tile[kk][c + j] = a[j] * wk;
            tile[kk][c + 4 + j] = b4[j] * wk;
        }
    }
    __syncthreads();
    {
        int d = t >> 2, kb2 = (t & 3) * 8;
        s16x8 o;
#pragma unroll
        for (int j = 0; j < 8; j++) o[j] = f2bf(tile[kb2 + j][d]);
        *(s16x8*)(vwt + ((size_t)bh * ND + d) * NS + k0 + kb2) = o;
    }
}

// ---------- pre-pass 3: K f32 -> bf16, 6.3 MB ----------
__global__ void kcast(const float* __restrict__ in, unsigned short* __restrict__ outp) {
    size_t t = (size_t)blockIdx.x * 256 + threadIdx.x;
    const float* p = in + t * 8;
    f32x4 a = *(const f32x4*)p;
    f32x4 b = *(const f32x4*)(p + 4);
    s16x8 o;
#pragma unroll
    for (int j = 0; j < 4; j++) {
        o[j] = f2bf(a[j]);
        o[4 + j] = f2bf(b[j]);
    }
    *(s16x8*)(outp + t * 8) = o;
}

// ---------- main: R11 (32-row tiles, 16 waves) + LDS-staged bitmask ----------
// WG = 1024 thr (16 waves), 32 q-rows, 1 WG/CU (146 KB LDS).
// Change vs R11: the WG's 8 KB mask-bit slab is cooperatively loaded into LDS
// (coalesced) before phase 1; the QK loop reads bits from LDS (broadcast)
// instead of issuing 16 scatter-gather global loads per wave. QK loop fully
// unrolled to deepen the K-load pipeline.
// Phase 1: all 16 waves QK own 128-k strip -> bf16 P in LDS + ssum.
// Phase 2: waves 0-3 PV (own 16-d tile, full k); waves 4-15 pure streamers.
__global__ __launch_bounds__(1024, 4) void attn_main(
    const float* __restrict__ Qg, const float* __restrict__ wg,
    const uint32_t* __restrict__ bitsg, const unsigned short* __restrict__ vwtg,
    const unsigned short* __restrict__ kbfg, float* __restrict__ outg,
    float* __restrict__ pg) {
    extern __shared__ char smem[];
    char* Pb = smem;                            // [32][4096 B] bf16 = 131072
    float* w_lds = (float*)(smem + 131072);     // [2048] f32 = 8192
    uint32_t* bits_l = (uint32_t*)(smem + 139264);  // [32][64] = 8192
    float* red = (float*)(smem + 147456);       // [16][32] = 2048
    float* rinv_sh = (float*)(smem + 149504);   // [32] = 128

    int bid = blockIdx.x;
    // XCD swizzle: 1536 WGs = 8 x 192 (bijective); 1.5 heads/XCD L2-resident
    int swz = (bid & 7) * 192 + (bid >> 3);
    int bh = swz >> 6;
    int qb = swz & 63;
    int b = bh / NH;
    int q0 = qb * 32;

    const unsigned short* kbfh = kbfg + (size_t)bh * NS * ND;
    const uint32_t* bitsb = bitsg + (size_t)b * (NS * (NS / 32));
    float* ph = pg + ((size_t)bh * NS + q0) * NS;
    float* outh = outg + (size_t)bh * NS * ND;

    int tid = threadIdx.x;
    int wv = tid >> 6, lane = tid & 63;
    int m = lane & 15, kb = lane >> 4;
    const int xm = (m & 7) << 4;  // == (q&7)<<4 for q = n*16+m

    // cooperative staging: w (8 KB) + bits slab (8 KB), coalesced
    if (tid < 512) *(f32x4*)(w_lds + tid * 4) = *(const f32x4*)(wg + tid * 4);
    {
        int q = tid >> 5, wp = (tid & 31) * 2;
        *(uint2*)(bits_l + q * 64 + wp) = *(const uint2*)(bitsb + (size_t)(q0 + q) * 64 + wp);
    }

    // Q fragments for both 16-row groups (1/8 folded)
    s16x8 qf[2][2];
#pragma unroll
    for (int n = 0; n < 2; n++)
#pragma unroll
        for (int ks = 0; ks < 2; ks++) {
            const float* src = Qg + ((size_t)bh * NS + q0 + n * 16 + m) * ND + ks * 32 + kb * 8;
            f32x4 a = *(const f32x4*)src;
            f32x4 c4 = *(const f32x4*)(src + 4);
            s16x8 f;
#pragma unroll
            for (int j = 0; j < 4; j++) {
                f[j] = f2bf(a[j] * 0.125f);
                f[4 + j] = f2bf(c4[j] * 0.125f);
            }
            qf[n][ks] = f;
        }
    __syncthreads();  // bits_l ready

    // ---- Phase 1: all 16 waves QK own 128-k strip (reads only) ----
    float ssum[2] = {0.f, 0.f};
    const int cbase = wv * 128;
#pragma unroll
    for (int kt = 0; kt < 8; kt++) {
        int krow = cbase + kt * 16;
        const unsigned short* kr = kbfh + (size_t)(krow + m) * ND + kb * 8;
        s16x8 kf0 = *(const s16x8*)kr;
        s16x8 kf1 = *(const s16x8*)(kr + 32);
        f32x4 c0 = {0.f, 0.f, 0.f, 0.f}, c1 = {0.f, 0.f, 0.f, 0.f};
        c0 = mfma16(kf0, qf[0][0], c0);
        c0 = mfma16(kf1, qf[0][1], c0);
        c1 = mfma16(kf0, qf[1][0], c1);
        c1 = mfma16(kf1, qf[1][1], c1);
        int kcol = krow + kb * 4;
        const int widx = kt * 16 + kb * 4;          // offset within strip
        const int word = wv * 4 + (widx >> 5);      // word index in row slab
        const int shr = widx & 31;
#pragma unroll
        for (int n = 0; n < 2; n++) {
            f32x4 c = n ? c1 : c0;
            int q = n * 16 + m;
            uint32_t keepbits = bits_l[q * 64 + word] >> shr;
            float p[4];
#pragma unroll
            for (int r = 0; r < 4; r++) {
                float s = c[r];
                bool keep = ((keepbits >> r) & 1u) && (s > 0.f);
                p[r] = keep ? s : 0.f;
                ssum[n] += p[r] * p[r];
            }
            uint2 u;
            u.x = (uint32_t)(unsigned short)f2bf(p[0]) |
                  ((uint32_t)(unsigned short)f2bf(p[1]) << 16);
            u.y = (uint32_t)(unsigned short)f2bf(p[2]) |
                  ((uint32_t)(unsigned short)f2bf(p[3]) << 16);
            *(uint2*)(Pb + q * 4096 + ((kcol * 2) ^ xm)) = u;
        }
    }
    ssum[0] += __shfl_xor(ssum[0], 16);
    ssum[0] += __shfl_xor(ssum[0], 32);
    ssum[1] += __shfl_xor(ssum[1], 16);
    ssum[1] += __shfl_xor(ssum[1], 32);
    if (lane < 16) {
        red[wv * 32 + lane] = ssum[0];
        red[wv * 32 + 16 + lane] = ssum[1];
    }
    __syncthreads();
    if (tid < 32) {
        float s = 0.f;
#pragma unroll
        for (int i = 0; i < 16; i++) s += red[i * 32 + tid];
        rinv_sh[tid] = 1.0f / sqrtf(s * (1.0f / NS) + 1e-6f);
    }
    __syncthreads();

    // ---- Phase 2 ----
    if (wv < 4) {
        // PV: wave owns d-tile dt over all 32 rows; vwt read once per WG
        const int dt = wv;
        const unsigned short* vrow = vwtg + ((size_t)bh * ND + dt * 16 + m) * NS;
        f32x4 acc[2][2];
#pragma unroll
        for (int n = 0; n < 2; n++)
#pragma unroll
            for (int h = 0; h < 2; h++) acc[n][h] = (f32x4){0.f, 0.f, 0.f, 0.f};
#pragma unroll 4
        for (int ks = 0; ks < 32; ks++) {
            int k0 = ks * 64;
            s16x8 af0 = *(const s16x8*)(vrow + k0 + kb * 8);
            s16x8 af1 = *(const s16x8*)(vrow + k0 + 32 + kb * 8);
#pragma unroll
            for (int n = 0; n < 2; n++) {
                int q = n * 16 + m;
                s16x8 b0 = *(const s16x8*)(Pb + q * 4096 + ((k0 * 2 + kb * 16) ^ xm));
                s16x8 b1 = *(const s16x8*)(Pb + q * 4096 + ((k0 * 2 + 64 + kb * 16) ^ xm));
                acc[n][0] = mfma16(af0, b0, acc[n][0]);
                acc[n][1] = mfma16(af1, b1, acc[n][1]);
            }
        }
#pragma unroll
        for (int n = 0; n < 2; n++) {
            int q = n * 16 + m;
            float ri = rinv_sh[q];
            f32x4 o = {(acc[n][0][0] + acc[n][1][0]) * ri, (acc[n][0][1] + acc[n][1][1]) * ri,
                       (acc[n][0][2] + acc[n][1][2]) * ri, (acc[n][0][3] + acc[n][1][3]) * ri};
            __builtin_nontemporal_store(
                o, (f32x4*)(outh + (size_t)(q0 + q) * ND + dt * 16 + kb * 4));
        }
    } else {
        // PURE STREAMERS: 12 waves, rows strided by 12; LDS reads + NT stores
        for (int r = wv - 4; r < 32; r += 12) {
            float ri = rinv_sh[r];
            int xr = (r & 7) << 4;
#pragma unroll
            for (int it = 0; it < 8; it++) {
                int colf = it * 256 + lane * 4;
                uint2 u = *(const uint2*)(Pb + r * 4096 + ((colf * 2) ^ xr));
                f32x4 w4 = *(const f32x4*)(w_lds + colf);
                f32x4 o;
                o[0] = bf2f((short)(u.x & 0xffff)) * w4[0] * ri;
                o[1] = bf2f((short)(u.x >> 16)) * w4[1] * ri;
                o[2] = bf2f((short)(u.y & 0xffff)) * w4[2] * ri;
                o[3] = bf2f((short)(u.y >> 16)) * w4[3] * ri;
                __builtin_nontemporal_store(o, (f32x4*)(ph + (size_t)r * NS + colf));
            }
        }
    }
}

// ---------- fallback (no workspace): fp32-exact per-row kernel ----------
__global__ void attn_fallback(const float* __restrict__ Qg, const float* __restrict__ Kg,
                              const float* __restrict__ Vg, const int* __restrict__ maskg,
                              const float* __restrict__ wg, float* __restrict__ outg,
                              float* __restrict__ pg) {
    __shared__ float qs[64];
    __shared__ float srow[2048];
    __shared__ float osum[64];
    __shared__ float red2[8];
    int bid = blockIdx.x;
    int bh = bid >> 11, q = bid & 2047, b = bh / NH;
    int tid = threadIdx.x;
    const float* Qr = Qg + ((size_t)bh * NS + q) * ND;
    const float* Kh = Kg + (size_t)bh * NS * ND;
    const float* Vh = Vg + (size_t)bh * NS * ND;
    const int* mrow = maskg + ((size_t)b * NS + q) * NS;
    if (tid < 64) {
        qs[tid] = Qr[tid] * 0.125f;
        osum[tid] = 0.f;
    }
    __syncthreads();
    float ss = 0.f;
    for (int k = tid; k < NS; k += 256) {
        float s = 0.f;
        const float* kr = Kh + (size_t)k * ND;
        for (int d = 0; d < ND; d++) s += qs[d] * kr[d];
        if (mrow[k] == 0 || s < 0.f) s = 0.f;
        srow[k] = s;
        ss += s * s;
    }
#pragma unroll
    for (int o = 32; o >= 1; o >>= 1) ss += __shfl_down(ss, o);
    if ((tid & 63) == 0) red2[tid >> 6] = ss;
    __syncthreads();
    float ri;
    {
        float tot = red2[0] + red2[1] + red2[2] + red2[3];
        ri = 1.0f / sqrtf(tot * (1.0f / NS) + 1e-6f);
    }
    for (int k = tid; k < NS; k += 256) {
        float pa = srow[k] * ri * wg[k];
        pg[(((size_t)bh * NS + q) * NS) + k] = pa;
        const float* vr = Vh + (size_t)k * ND;
        for (int d = 0; d < ND; d++) atomicAdd(&osum[d], pa * vr[d]);
    }
    __syncthreads();
    if (tid < 64) outg[((size_t)bh * NS + q) * ND + tid] = osum[tid];
}

extern "C" void kernel_launch(void* const* d_in, const int* in_sizes, int n_in,
                              void* d_out, int out_size, void* d_ws, size_t ws_size,
                              hipStream_t stream) {
    const float* Q = (const float*)d_in[0];
    const float* K = (const float*)d_in[1];
    const float* V = (const float*)d_in[2];
    const int* mask = (const int*)d_in[3];
    const float* w = (const float*)d_in[4];
    float* out = (float*)d_out;
    float* pattn = out + (size_t)NB * NH * NS * ND;

    const size_t bits_bytes = (size_t)NB * NS * (NS / 32) * sizeof(uint32_t);     // 1 MB
    const size_t vwt_bytes = (size_t)NB * NH * ND * NS * sizeof(unsigned short);  // 6.3 MB
    const size_t kbf_bytes = vwt_bytes;                                           // 6.3 MB
    const int nwg = NB * NH * (NS / 32);  // 1536
    const int smem = 131072 + 8192 + 8192 + 2048 + 128;  // 149632 B

    if (ws_size >= bits_bytes + vwt_bytes + kbf_bytes) {
        char* wsb = (char*)d_ws;
        uint32_t* bits = (uint32_t*)wsb;
        unsigned short* vwt = (unsigned short*)(wsb + bits_bytes);
        unsigned short* kbf = (unsigned short*)(wsb + bits_bytes + vwt_bytes);
        kbits<<<(NB * NS * NS / 32) / 256, 256, 0, stream>>>(mask, bits);
        kcast<<<(NB * NH * NS * ND) / (256 * 8), 256, 0, stream>>>(K, kbf);
        kvwt<<<NB * NH * (NS / 32), 256, 0, stream>>>(V, w, vwt);
        hipFuncSetAttribute(reinterpret_cast<const void*>(&attn_main),
                            hipFuncAttributeMaxDynamicSharedMemorySize, smem);
        attn_main<<<nwg, 1024, smem, stream>>>(Q, w, bits, vwt, kbf, out, pattn);
    } else {
        attn_fallback<<<NB * NH * NS, 256, 0, stream>>>(Q, K, V, mask, w, out, pattn);
    }
}

// Round 14
// 163.313 us; speedup vs baseline: 1.3174x; 1.0149x over previous
//
#include <hip/hip_runtime.h>
#include <stdint.h>

#define NB 2
#define NH 12
#define NS 2048
#define ND 64

typedef __attribute__((ext_vector_type(4))) float f32x4;
typedef __attribute__((ext_vector_type(8))) short s16x8;

__device__ __forceinline__ short f2bf(float x) {
    return __builtin_bit_cast(short, (__bf16)x);
}
__device__ __forceinline__ float bf2f(short h) {
    uint32_t u = ((uint32_t)(unsigned short)h) << 16;
    return __builtin_bit_cast(float, u);
}
__device__ __forceinline__ f32x4 mfma16(s16x8 a, s16x8 b, f32x4 c) {
    return __builtin_amdgcn_mfma_f32_16x16x32_bf16(a, b, c, 0, 0, 0);
}

// ---------- merged pre-pass: bits | kcast | vwt in one launch ----------
// blocks [0,1024): mask int32 -> bitmask (1 MB)
// blocks [1024,2560): K f32 -> bf16 (6.3 MB)
// blocks [2560,4096): VwT[b,h,d,k] = V[k,d]*w[k] bf16 (6.3 MB)
__global__ void kprep(const int* __restrict__ maskg, const float* __restrict__ Kg,
                      const float* __restrict__ Vg, const float* __restrict__ wg,
                      uint32_t* __restrict__ bits, unsigned short* __restrict__ kbf,
                      unsigned short* __restrict__ vwt) {
    __shared__ float tile[32][65];
    int bid = blockIdx.x;
    int t = threadIdx.x;
    if (bid < 1024) {
        int wi = bid * 256 + t;
        const int* mp = maskg + (size_t)wi * 32;
        uint32_t v = 0;
#pragma unroll
        for (int i = 0; i < 8; i++) {
            int4 q = *(const int4*)(mp + i * 4);
            v |= ((uint32_t)(q.x != 0) << (i * 4)) | ((uint32_t)(q.y != 0) << (i * 4 + 1)) |
                 ((uint32_t)(q.z != 0) << (i * 4 + 2)) | ((uint32_t)(q.w != 0) << (i * 4 + 3));
        }
        bits[wi] = v;
    } else if (bid < 2560) {
        size_t tt = (size_t)(bid - 1024) * 256 + t;
        const float* p = Kg + tt * 8;
        f32x4 a = *(const f32x4*)p;
        f32x4 b = *(const f32x4*)(p + 4);
        s16x8 o;
#pragma unroll
        for (int j = 0; j < 4; j++) {
            o[j] = f2bf(a[j]);
            o[4 + j] = f2bf(b[j]);
        }
        *(s16x8*)(kbf + tt * 8) = o;
    } else {
        int blk = bid - 2560;
        int bh = blk >> 6;
        int k0 = (blk & 63) * 32;
        const float* Vh = Vg + ((size_t)bh * NS + k0) * ND;
        {
            int kk = t >> 3, c = (t & 7) * 8;
            f32x4 a = *(const f32x4*)(Vh + kk * ND + c);
            f32x4 b4 = *(const f32x4*)(Vh + kk * ND + c + 4);
            float wk = wg[k0 + kk];
#pragma unroll
            for (int j = 0; j < 4; j++) {
                tile[kk][c + j] = a[j] * wk;
                tile[kk][c + 4 + j] = b4[j] * wk;
            }
        }
        __syncthreads();
        {
            int d = t >> 2, kb2 = (t & 3) * 8;
            s16x8 o;
#pragma unroll
            for (int j = 0; j < 8; j++) o[j] = f2bf(tile[kb2 + j][d]);
            *(s16x8*)(vwt + ((size_t)bh * ND + d) * NS + k0 + kb2) = o;
        }
    }
}

// ---------- main: R13 + merged streamer tweaks ----------
// WG = 1024 thr (16 waves), 32 q-rows, 1 WG/CU (~146 KB LDS).
// Phase 1: all 16 waves QK own 128-k strip -> bf16 P in LDS (XOR (q&7)<<4)
//          + ssum; bits slab pre-staged in LDS (coalesced, R13 win).
// Phase 2: waves 0-3 PV (own 16-d tile, full k), then each streams 1 row
//          (28+wv); waves 4-15 stream rows 0..27 with w4 hoisted to regs.
__global__ __launch_bounds__(1024, 4) void attn_main(
    const float* __restrict__ Qg, const float* __restrict__ wg,
    const uint32_t* __restrict__ bitsg, const unsigned short* __restrict__ vwtg,
    const unsigned short* __restrict__ kbfg, float* __restrict__ outg,
    float* __restrict__ pg) {
    extern __shared__ char smem[];
    char* Pb = smem;                                // [32][4096 B] bf16 = 131072
    float* w_lds = (float*)(smem + 131072);         // [2048] f32 = 8192
    uint32_t* bits_l = (uint32_t*)(smem + 139264);  // [32][64] = 8192
    float* red = (float*)(smem + 147456);           // [16][32] = 2048
    float* rinv_sh = (float*)(smem + 149504);       // [32] = 128

    int bid = blockIdx.x;
    // XCD swizzle: 1536 WGs = 8 x 192 (bijective); 1.5 heads/XCD L2-resident
    int swz = (bid & 7) * 192 + (bid >> 3);
    int bh = swz >> 6;
    int qb = swz & 63;
    int b = bh / NH;
    int q0 = qb * 32;

    const unsigned short* kbfh = kbfg + (size_t)bh * NS * ND;
    const uint32_t* bitsb = bitsg + (size_t)b * (NS * (NS / 32));
    float* ph = pg + ((size_t)bh * NS + q0) * NS;
    float* outh = outg + (size_t)bh * NS * ND;

    int tid = threadIdx.x;
    int wv = tid >> 6, lane = tid & 63;
    int m = lane & 15, kb = lane >> 4;
    const int xm = (m & 7) << 4;  // == (q&7)<<4 for q = n*16+m

    // cooperative staging: w (8 KB) + bits slab (8 KB), coalesced
    if (tid < 512) *(f32x4*)(w_lds + tid * 4) = *(const f32x4*)(wg + tid * 4);
    {
        int q = tid >> 5, wp = (tid & 31) * 2;
        *(uint2*)(bits_l + q * 64 + wp) = *(const uint2*)(bitsb + (size_t)(q0 + q) * 64 + wp);
    }

    // Q fragments for both 16-row groups (1/8 folded)
    s16x8 qf[2][2];
#pragma unroll
    for (int n = 0; n < 2; n++)
#pragma unroll
        for (int ks = 0; ks < 2; ks++) {
            const float* src = Qg + ((size_t)bh * NS + q0 + n * 16 + m) * ND + ks * 32 + kb * 8;
            f32x4 a = *(const f32x4*)src;
            f32x4 c4 = *(const f32x4*)(src + 4);
            s16x8 f;
#pragma unroll
            for (int j = 0; j < 4; j++) {
                f[j] = f2bf(a[j] * 0.125f);
                f[4 + j] = f2bf(c4[j] * 0.125f);
            }
            qf[n][ks] = f;
        }
    __syncthreads();  // bits_l ready

    // ---- Phase 1: all 16 waves QK own 128-k strip (reads only) ----
    float ssum[2] = {0.f, 0.f};
    const int cbase = wv * 128;
#pragma unroll
    for (int kt = 0; kt < 8; kt++) {
        int krow = cbase + kt * 16;
        const unsigned short* kr = kbfh + (size_t)(krow + m) * ND + kb * 8;
        s16x8 kf0 = *(const s16x8*)kr;
        s16x8 kf1 = *(const s16x8*)(kr + 32);
        f32x4 c0 = {0.f, 0.f, 0.f, 0.f}, c1 = {0.f, 0.f, 0.f, 0.f};
        c0 = mfma16(kf0, qf[0][0], c0);
        c0 = mfma16(kf1, qf[0][1], c0);
        c1 = mfma16(kf0, qf[1][0], c1);
        c1 = mfma16(kf1, qf[1][1], c1);
        int kcol = krow + kb * 4;
        const int widx = kt * 16 + kb * 4;      // offset within strip
        const int word = wv * 4 + (widx >> 5);  // word index in row slab
        const int shr = widx & 31;
#pragma unroll
        for (int n = 0; n < 2; n++) {
            f32x4 c = n ? c1 : c0;
            int q = n * 16 + m;
            uint32_t keepbits = bits_l[q * 64 + word] >> shr;
            float p[4];
#pragma unroll
            for (int r = 0; r < 4; r++) {
                float s = c[r];
                bool keep = ((keepbits >> r) & 1u) && (s > 0.f);
                p[r] = keep ? s : 0.f;
                ssum[n] += p[r] * p[r];
            }
            uint2 u;
            u.x = (uint32_t)(unsigned short)f2bf(p[0]) |
                  ((uint32_t)(unsigned short)f2bf(p[1]) << 16);
            u.y = (uint32_t)(unsigned short)f2bf(p[2]) |
                  ((uint32_t)(unsigned short)f2bf(p[3]) << 16);
            *(uint2*)(Pb + q * 4096 + ((kcol * 2) ^ xm)) = u;
        }
    }
    ssum[0] += __shfl_xor(ssum[0], 16);
    ssum[0] += __shfl_xor(ssum[0], 32);
    ssum[1] += __shfl_xor(ssum[1], 16);
    ssum[1] += __shfl_xor(ssum[1], 32);
    if (lane < 16) {
        red[wv * 32 + lane] = ssum[0];
        red[wv * 32 + 16 + lane] = ssum[1];
    }
    __syncthreads();
    if (tid < 32) {
        float s = 0.f;
#pragma unroll
        for (int i = 0; i < 16; i++) s += red[i * 32 + tid];
        rinv_sh[tid] = 1.0f / sqrtf(s * (1.0f / NS) + 1e-6f);
    }
    __syncthreads();

    // ---- Phase 2 ----
    if (wv < 4) {
        // PV: wave owns d-tile dt over all 32 rows; vwt read once per WG
        const int dt = wv;
        const unsigned short* vrow = vwtg + ((size_t)bh * ND + dt * 16 + m) * NS;
        f32x4 acc[2][2];
#pragma unroll
        for (int n = 0; n < 2; n++)
#pragma unroll
            for (int h = 0; h < 2; h++) acc[n][h] = (f32x4){0.f, 0.f, 0.f, 0.f};
#pragma unroll 4
        for (int ks = 0; ks < 32; ks++) {
            int k0 = ks * 64;
            s16x8 af0 = *(const s16x8*)(vrow + k0 + kb * 8);
            s16x8 af1 = *(const s16x8*)(vrow + k0 + 32 + kb * 8);
#pragma unroll
            for (int n = 0; n < 2; n++) {
                int q = n * 16 + m;
                s16x8 b0 = *(const s16x8*)(Pb + q * 4096 + ((k0 * 2 + kb * 16) ^ xm));
                s16x8 b1 = *(const s16x8*)(Pb + q * 4096 + ((k0 * 2 + 64 + kb * 16) ^ xm));
                acc[n][0] = mfma16(af0, b0, acc[n][0]);
                acc[n][1] = mfma16(af1, b1, acc[n][1]);
            }
        }
#pragma unroll
        for (int n = 0; n < 2; n++) {
            int q = n * 16 + m;
            float ri = rinv_sh[q];
            f32x4 o = {(acc[n][0][0] + acc[n][1][0]) * ri, (acc[n][0][1] + acc[n][1][1]) * ri,
                       (acc[n][0][2] + acc[n][1][2]) * ri, (acc[n][0][3] + acc[n][1][3]) * ri};
            __builtin_nontemporal_store(
                o, (f32x4*)(outh + (size_t)(q0 + q) * ND + dt * 16 + kb * 4));
        }
        // then stream one row (28+wv)
        {
            int r = 28 + wv;
            float ri = rinv_sh[r];
            int xr = (r & 7) << 4;
#pragma unroll
            for (int it = 0; it < 8; it++) {
                int colf = it * 256 + lane * 4;
                uint2 u = *(const uint2*)(Pb + r * 4096 + ((colf * 2) ^ xr));
                f32x4 w4 = *(const f32x4*)(w_lds + colf);
                f32x4 o;
                o[0] = bf2f((short)(u.x & 0xffff)) * w4[0] * ri;
                o[1] = bf2f((short)(u.x >> 16)) * w4[1] * ri;
                o[2] = bf2f((short)(u.y & 0xffff)) * w4[2] * ri;
                o[3] = bf2f((short)(u.y >> 16)) * w4[3] * ri;
                __builtin_nontemporal_store(o, (f32x4*)(ph + (size_t)r * NS + colf));
            }
        }
    } else {
        // STREAMERS: 12 waves cover rows 0..27; w4 hoisted to registers
        int s = wv - 4;
        f32x4 wr[8];
#pragma unroll
        for (int it = 0; it < 8; it++) wr[it] = *(const f32x4*)(w_lds + it * 256 + lane * 4);
        for (int r = s; r < 28; r += 12) {
            float ri = rinv_sh[r];
            int xr = (r & 7) << 4;
#pragma unroll
            for (int it = 0; it < 8; it++) {
                int colf = it * 256 + lane * 4;
                uint2 u = *(const uint2*)(Pb + r * 4096 + ((colf * 2) ^ xr));
                f32x4 o;
                o[0] = bf2f((short)(u.x & 0xffff)) * wr[it][0] * ri;
                o[1] = bf2f((short)(u.x >> 16)) * wr[it][1] * ri;
                o[2] = bf2f((short)(u.y & 0xffff)) * wr[it][2] * ri;
                o[3] = bf2f((short)(u.y >> 16)) * wr[it][3] * ri;
                __builtin_nontemporal_store(o, (f32x4*)(ph + (size_t)r * NS + colf));
            }
        }
    }
}

// ---------- fallback (no workspace): fp32-exact per-row kernel ----------
__global__ void attn_fallback(const float* __restrict__ Qg, const float* __restrict__ Kg,
                              const float* __restrict__ Vg, const int* __restrict__ maskg,
                              const float* __restrict__ wg, float* __restrict__ outg,
                              float* __restrict__ pg) {
    __shared__ float qs[64];
    __shared__ float srow[2048];
    __shared__ float osum[64];
    __shared__ float red2[8];
    int bid = blockIdx.x;
    int bh = bid >> 11, q = bid & 2047, b = bh / NH;
    int tid = threadIdx.x;
    const float* Qr = Qg + ((size_t)bh * NS + q) * ND;
    const float* Kh = Kg + (size_t)bh * NS * ND;
    const float* Vh = Vg + (size_t)bh * NS * ND;
    const int* mrow = maskg + ((size_t)b * NS + q) * NS;
    if (tid < 64) {
        qs[tid] = Qr[tid] * 0.125f;
        osum[tid] = 0.f;
    }
    __syncthreads();
    float ss = 0.f;
    for (int k = tid; k < NS; k += 256) {
        float s = 0.f;
        const float* kr = Kh + (size_t)k * ND;
        for (int d = 0; d < ND; d++) s += qs[d] * kr[d];
        if (mrow[k] == 0 || s < 0.f) s = 0.f;
        srow[k] = s;
        ss += s * s;
    }
#pragma unroll
    for (int o = 32; o >= 1; o >>= 1) ss += __shfl_down(ss, o);
    if ((tid & 63) == 0) red2[tid >> 6] = ss;
    __syncthreads();
    float ri;
    {
        float tot = red2[0] + red2[1] + red2[2] + red2[3];
        ri = 1.0f / sqrtf(tot * (1.0f / NS) + 1e-6f);
    }
    for (int k = tid; k < NS; k += 256) {
        float pa = srow[k] * ri * wg[k];
        pg[(((size_t)bh * NS + q) * NS) + k] = pa;
        const float* vr = Vh + (size_t)k * ND;
        for (int d = 0; d < ND; d++) atomicAdd(&osum[d], pa * vr[d]);
    }
    __syncthreads();
    if (tid < 64) outg[((size_t)bh * NS + q) * ND + tid] = osum[tid];
}

extern "C" void kernel_launch(void* const* d_in, const int* in_sizes, int n_in,
                              void* d_out, int out_size, void* d_ws, size_t ws_size,
                              hipStream_t stream) {
    const float* Q = (const float*)d_in[0];
    const float* K = (const float*)d_in[1];
    const float* V = (const float*)d_in[2];
    const int* mask = (const int*)d_in[3];
    const float* w = (const float*)d_in[4];
    float* out = (float*)d_out;
    float* pattn = out + (size_t)NB * NH * NS * ND;

    const size_t bits_bytes = (size_t)NB * NS * (NS / 32) * sizeof(uint32_t);     // 1 MB
    const size_t vwt_bytes = (size_t)NB * NH * ND * NS * sizeof(unsigned short);  // 6.3 MB
    const size_t kbf_bytes = vwt_bytes;                                           // 6.3 MB
    const int nwg = NB * NH * (NS / 32);                 // 1536
    const int smem = 131072 + 8192 + 8192 + 2048 + 128;  // 149632 B

    if (ws_size >= bits_bytes + vwt_bytes + kbf_bytes) {
        char* wsb = (char*)d_ws;
        uint32_t* bits = (uint32_t*)wsb;
        unsigned short* vwt = (unsigned short*)(wsb + bits_bytes);
        unsigned short* kbf = (unsigned short*)(wsb + bits_bytes + vwt_bytes);
        kprep<<<4096, 256, 0, stream>>>(mask, K, V, w, bits, kbf, vwt);
        hipFuncSetAttribute(reinterpret_cast<const void*>(&attn_main),
                            hipFuncAttributeMaxDynamicSharedMemorySize, smem);
        attn_main<<<nwg, 1024, smem, stream>>>(Q, w, bits, vwt, kbf, out, pattn);
    } else {
        attn_fallback<<<NB * NH * NS, 256, 0, stream>>>(Q, K, V, mask, w, out, pattn);
    }
}